// Round 1
// baseline (576.087 us; speedup 1.0000x reference)
//
#include <hip/hip_runtime.h>

// NeRF hierarchical sampler: one wave64 per ray, 4 rays per 256-thread block.
// Per-wave LDS layout (stride 516 floats, 16B-aligned so allz can be float4-read):
//   [0..191]   srt   : sorted 192 z values
//   [192..383] allz  : coarse(64) + fine(128) z values (float4-aligned)
//   [384..448] cdf   : 65-entry CDF
//   [449..513] edg   : 65-entry z_edges
#define NC 64
#define NF 128
#define NT 192
#define WAVES 4
#define STRIDE 516

__global__ __launch_bounds__(256) void hier_sampler(
    const float* __restrict__ org, const float* __restrict__ dir,
    const float* __restrict__ dens, const float* __restrict__ trand,
    const float* __restrict__ uu, float* __restrict__ out_pts,
    float* __restrict__ out_z)
{
    const int lane = threadIdx.x & 63;
    const int w    = threadIdx.x >> 6;
    const int ray  = blockIdx.x * WAVES + w;

    __shared__ __align__(16) float lds[WAVES][STRIDE];
    float* srt  = &lds[w][0];
    float* allz = &lds[w][192];
    float* cdf  = &lds[w][384];
    float* edg  = &lds[w][449];

    // ---- coarse stratified sampling ----
    const float step = 4.0f / 63.0f;
    float zg  = 2.0f + step * (float)lane;
    float zgn = 2.0f + step * (float)(lane + 1);
    float zgp = 2.0f + step * (float)(lane - 1);
    float mid  = 0.5f * (zg + zgn);   // mids[lane]   (valid lane<63)
    float midp = 0.5f * (zg + zgp);   // mids[lane-1] (valid lane>=1)
    float lower = (lane == 0)  ? 2.0f : midp;
    float upper = (lane == 63) ? 6.0f : mid;
    float t  = trand[(size_t)ray * NC + lane];
    float zv = lower + (upper - lower) * t;

    float znext = __shfl_down(zv, 1);
    float zprev = __shfl_up(zv, 1);
    float delta = (lane == 63) ? 1e10f : (znext - zv);

    // ---- transmittance weights ----
    float dv = dens[(size_t)ray * NC + lane];
    float a  = 1.0f - expf(-dv * delta);
    float q  = 1.0f - a + 1e-10f;

    // inclusive prefix product over the wave
    float P = q;
    #pragma unroll
    for (int off = 1; off < 64; off <<= 1) {
        float n = __shfl_up(P, off);
        if (lane >= off) P *= n;
    }
    float T = __shfl_up(P, 1);
    if (lane == 0) T = 1.0f;
    float wgt = a * T;
    float ww  = wgt + 1e-5f;

    // inclusive prefix sum over the wave
    float S = ww;
    #pragma unroll
    for (int off = 1; off < 64; off <<= 1) {
        float n = __shfl_up(S, off);
        if (lane >= off) S += n;
    }
    float total = __shfl(S, 63);
    cdf[lane + 1] = S / total;
    if (lane == 0) cdf[0] = 0.0f;

    // ---- z_edges (65 entries) ----
    float e = (lane == 0) ? (zv - 0.5f * (znext - zv)) : (0.5f * (zv + zprev));
    edg[lane] = e;
    if (lane == 63) edg[64] = zv + 0.5f * (zv - zprev);

    allz[lane] = zv;   // coarse z (sorted)
    __syncthreads();

    // ---- inverse-CDF fine sampling: 2 u's per lane ----
    float fz[2];
    #pragma unroll
    for (int h = 0; h < 2; ++h) {
        int j = lane + h * 64;
        float uv = uu[(size_t)ray * NF + j];
        // searchsorted(cdf, uv, side='right') over 65 entries, fixed 7 steps
        int lo = 0, hi = 65;
        #pragma unroll
        for (int it = 0; it < 7; ++it) {
            int m = (lo + hi) >> 1;
            bool c = cdf[m] <= uv;
            lo = c ? m + 1 : lo;
            hi = c ? hi : m;
        }
        int below = lo - 1; below = below < 0 ? 0 : (below > 64 ? 64 : below);
        int above = lo > 64 ? 64 : lo;
        float c0 = cdf[below], c1 = cdf[above];
        float e0 = edg[below], e1 = edg[above];
        float dn = c1 - c0;
        if (dn < 1e-5f) dn = 1.0f;
        float tt = (uv - c0) / dn;
        fz[h] = e0 + tt * (e1 - e0);
        allz[64 + j] = fz[h];
    }
    __syncthreads();

    // ---- rank-by-counting sort of 192 z values (3 keys per lane) ----
    float k0 = zv, k1 = fz[0], k2 = fz[1];
    int   i0 = lane, i1 = 64 + lane, i2 = 128 + lane;
    int   r0 = 0, r1 = 0, r2 = 0;
    const float4* az4 = (const float4*)allz;
    #pragma unroll 4
    for (int m4 = 0; m4 < NT / 4; ++m4) {
        float4 v = az4[m4];     // uniform address -> LDS broadcast, no conflict
        int mb = m4 * 4;
        r0 += (v.x < k0) || (v.x == k0 && mb     < i0);
        r1 += (v.x < k1) || (v.x == k1 && mb     < i1);
        r2 += (v.x < k2) || (v.x == k2 && mb     < i2);
        r0 += (v.y < k0) || (v.y == k0 && mb + 1 < i0);
        r1 += (v.y < k1) || (v.y == k1 && mb + 1 < i1);
        r2 += (v.y < k2) || (v.y == k2 && mb + 1 < i2);
        r0 += (v.z < k0) || (v.z == k0 && mb + 2 < i0);
        r1 += (v.z < k1) || (v.z == k1 && mb + 2 < i1);
        r2 += (v.z < k2) || (v.z == k2 && mb + 2 < i2);
        r0 += (v.w < k0) || (v.w == k0 && mb + 3 < i0);
        r1 += (v.w < k1) || (v.w == k1 && mb + 3 < i1);
        r2 += (v.w < k2) || (v.w == k2 && mb + 3 < i2);
    }
    srt[r0] = k0;
    srt[r1] = k1;
    srt[r2] = k2;
    __syncthreads();

    // ---- emit points (o + d*z from sorted z) and sorted z, coalesced ----
    float ox = org[(size_t)ray * 3 + 0], oy = org[(size_t)ray * 3 + 1], oz = org[(size_t)ray * 3 + 2];
    float dx = dir[(size_t)ray * 3 + 0], dy = dir[(size_t)ray * 3 + 1], dz = dir[(size_t)ray * 3 + 2];

    size_t pbase = (size_t)ray * (NT * 3);
    #pragma unroll
    for (int it = 0; it < 9; ++it) {
        int idx = it * 64 + lane;          // 0..575
        int k = idx / 3;
        int c = idx - k * 3;
        float z = srt[k];
        float o_ = (c == 0) ? ox : ((c == 1) ? oy : oz);
        float d_ = (c == 0) ? dx : ((c == 1) ? dy : dz);
        out_pts[pbase + idx] = o_ + d_ * z;
    }
    size_t zbase = (size_t)ray * NT;
    #pragma unroll
    for (int it = 0; it < 3; ++it) {
        out_z[zbase + it * 64 + lane] = srt[it * 64 + lane];
    }
}

extern "C" void kernel_launch(void* const* d_in, const int* in_sizes, int n_in,
                              void* d_out, int out_size, void* d_ws, size_t ws_size,
                              hipStream_t stream) {
    const float* org   = (const float*)d_in[0];
    const float* dir   = (const float*)d_in[1];
    const float* dens  = (const float*)d_in[2];
    const float* trand = (const float*)d_in[3];
    const float* uv    = (const float*)d_in[4];
    int B = in_sizes[0] / 3;   // 131072

    float* out_pts = (float*)d_out;
    float* out_z   = out_pts + (size_t)B * (NT * 3);

    dim3 grid(B / WAVES), block(256);
    hipLaunchKernelGGL(hier_sampler, grid, block, 0, stream,
                       org, dir, dens, trand, uv, out_pts, out_z);
}

// Round 4
// 192.799 us; speedup vs baseline: 2.9880x; 2.9880x over previous
//
#include <hip/hip_runtime.h>

// NeRF hierarchical sampler: one wave64 per ray, 4 rays per 256-thread block.
// Sort: single padded 256-element register bitonic (4 values per lane).
// Per-wave LDS layout (stride 392 floats, 16B-aligned):
//   [0..255]   srt : sorted 256 values (positions 192..255 are 1e30 pads)
//   [256..320] cdf : 65-entry CDF
//   [321..385] edg : 65-entry z_edges
#define NC 64
#define NF 128
#define NT 192
#define WAVES 4
#define STRIDE 392

#define CE(a, b, dir) { float _lo = fminf(a, b), _hi = fmaxf(a, b); \
                        a = (dir) ? _lo : _hi; b = (dir) ? _hi : _lo; }

__global__ __launch_bounds__(256) void hier_sampler(
    const float* __restrict__ org, const float* __restrict__ dir,
    const float* __restrict__ dens, const float* __restrict__ trand,
    const float* __restrict__ uu, float* __restrict__ out_pts,
    float* __restrict__ out_z)
{
    const int lane = threadIdx.x & 63;
    const int w    = threadIdx.x >> 6;
    const int ray  = blockIdx.x * WAVES + w;

    __shared__ __align__(16) float lds[WAVES][STRIDE];
    float* srt = &lds[w][0];
    float* cdf = &lds[w][256];
    float* edg = &lds[w][321];

    // ---- coarse stratified sampling ----
    const float step = 4.0f / 63.0f;
    float zg  = 2.0f + step * (float)lane;
    float zgn = 2.0f + step * (float)(lane + 1);
    float zgp = 2.0f + step * (float)(lane - 1);
    float mid  = 0.5f * (zg + zgn);   // mids[lane]   (valid lane<63)
    float midp = 0.5f * (zg + zgp);   // mids[lane-1] (valid lane>=1)
    float lower = (lane == 0)  ? 2.0f : midp;
    float upper = (lane == 63) ? 6.0f : mid;
    float t  = trand[(size_t)ray * NC + lane];
    float zv = lower + (upper - lower) * t;

    float znext = __shfl_down(zv, 1);
    float zprev = __shfl_up(zv, 1);
    float delta = (lane == 63) ? 1e10f : (znext - zv);

    // ---- transmittance weights ----
    float dv = dens[(size_t)ray * NC + lane];
    float a  = 1.0f - expf(-dv * delta);
    float q  = 1.0f - a + 1e-10f;

    // inclusive prefix product over the wave
    float P = q;
    #pragma unroll
    for (int off = 1; off < 64; off <<= 1) {
        float n = __shfl_up(P, off);
        if (lane >= off) P *= n;
    }
    float T = __shfl_up(P, 1);
    if (lane == 0) T = 1.0f;
    float wgt = a * T;
    float ww  = wgt + 1e-5f;

    // inclusive prefix sum over the wave
    float S = ww;
    #pragma unroll
    for (int off = 1; off < 64; off <<= 1) {
        float n = __shfl_up(S, off);
        if (lane >= off) S += n;
    }
    float total = __shfl(S, 63);
    cdf[lane + 1] = S / total;
    if (lane == 0) cdf[0] = 0.0f;

    // ---- z_edges (65 entries) ----
    float e = (lane == 0) ? (zv - 0.5f * (znext - zv)) : (0.5f * (zv + zprev));
    edg[lane] = e;
    if (lane == 63) edg[64] = zv + 0.5f * (zv - zprev);
    __syncthreads();

    // ---- inverse-CDF fine sampling: 2 u's per lane ----
    float f0, f1;
    #pragma unroll
    for (int h = 0; h < 2; ++h) {
        int j = lane + h * 64;
        float uv = uu[(size_t)ray * NF + j];
        // searchsorted(cdf, uv, side='right') over 65 entries, 7 steps
        int lo = 0, hi = 65;
        #pragma unroll
        for (int it = 0; it < 7; ++it) {
            int m = (lo + hi) >> 1;
            bool c = cdf[m] <= uv;
            lo = c ? m + 1 : lo;
            hi = c ? hi : m;
        }
        int below = lo - 1; below = below < 0 ? 0 : (below > 64 ? 64 : below);
        int above = lo > 64 ? 64 : lo;
        float c0 = cdf[below], c1 = cdf[above];
        float e0 = edg[below], e1 = edg[above];
        float dn = c1 - c0;
        if (dn < 1e-5f) dn = 1.0f;
        float tt = (uv - c0) / dn;
        float fzv = e0 + tt * (e1 - e0);
        if (h == 0) f0 = fzv; else f1 = fzv;
    }

    // ---- padded 256-element bitonic sort, 4 values/lane, element e = 4*lane+h ----
    float x0 = zv, x1 = f0, x2 = f1, x3 = 1.0e30f;

    // k = 2 stage: pair (e, e^1); asc = ((e&2)==0) -> (x0,x1) asc, (x2,x3) desc
    CE(x0, x1, true);
    CE(x2, x3, false);

    #pragma unroll
    for (int k = 4; k <= 256; k <<= 1) {
        const bool asc = ((lane & (k >> 2)) == 0);   // ((4*lane) & k) == 0
        #pragma unroll
        for (int j = k >> 1; j >= 4; j >>= 1) {
            const int lm = j >> 2;                   // partner lane = lane ^ lm
            const bool tmin = (((lane & lm) == 0) == asc);
            float p;
            p = __shfl_xor(x0, lm); x0 = tmin ? fminf(x0, p) : fmaxf(x0, p);
            p = __shfl_xor(x1, lm); x1 = tmin ? fminf(x1, p) : fmaxf(x1, p);
            p = __shfl_xor(x2, lm); x2 = tmin ? fminf(x2, p) : fmaxf(x2, p);
            p = __shfl_xor(x3, lm); x3 = tmin ? fminf(x3, p) : fmaxf(x3, p);
        }
        // j == 2: pairs (x0,x2), (x1,x3)
        CE(x0, x2, asc);
        CE(x1, x3, asc);
        // j == 1: pairs (x0,x1), (x2,x3)
        CE(x0, x1, asc);
        CE(x2, x3, asc);
    }

    ((float4*)srt)[lane] = make_float4(x0, x1, x2, x3);
    __syncthreads();

    // ---- emit points (o + d*z from sorted z) and sorted z, coalesced ----
    float ox = org[(size_t)ray * 3 + 0], oy = org[(size_t)ray * 3 + 1], oz = org[(size_t)ray * 3 + 2];
    float dx = dir[(size_t)ray * 3 + 0], dy = dir[(size_t)ray * 3 + 1], dz = dir[(size_t)ray * 3 + 2];

    size_t pbase = (size_t)ray * (NT * 3);
    #pragma unroll
    for (int it = 0; it < 9; ++it) {
        int idx = it * 64 + lane;          // 0..575
        int k = idx / 3;
        int c = idx - k * 3;
        float z = srt[k];
        float o_ = (c == 0) ? ox : ((c == 1) ? oy : oz);
        float d_ = (c == 0) ? dx : ((c == 1) ? dy : dz);
        out_pts[pbase + idx] = o_ + d_ * z;
    }
    size_t zbase = (size_t)ray * NT;
    #pragma unroll
    for (int it = 0; it < 3; ++it) {
        out_z[zbase + it * 64 + lane] = srt[it * 64 + lane];
    }
}

extern "C" void kernel_launch(void* const* d_in, const int* in_sizes, int n_in,
                              void* d_out, int out_size, void* d_ws, size_t ws_size,
                              hipStream_t stream) {
    const float* org   = (const float*)d_in[0];
    const float* dir   = (const float*)d_in[1];
    const float* dens  = (const float*)d_in[2];
    const float* trand = (const float*)d_in[3];
    const float* uv    = (const float*)d_in[4];
    int B = in_sizes[0] / 3;   // 131072

    float* out_pts = (float*)d_out;
    float* out_z   = out_pts + (size_t)B * (NT * 3);

    dim3 grid(B / WAVES), block(256);
    hipLaunchKernelGGL(hier_sampler, grid, block, 0, stream,
                       org, dir, dens, trand, uv, out_pts, out_z);
}

// Round 6
// 144.564 us; speedup vs baseline: 3.9850x; 1.3337x over previous
//
#include <hip/hip_runtime.h>

// NeRF hierarchical sampler: 16 lanes per ray, 4 rays per wave64, 2 waves/block.
// All LDS traffic is wave-private (16-lane ray groups) -> no barriers needed.
// Per-ray LDS (RSTR=324 floats, 16B-aligned):
//   [0..191]   srt  : staging (coarse 64 + fine 128), later the sorted 192
//   [192..255] cdfB : cdf[1..64]  (cdf[0]=0 handled implicitly: u>=0 always)
//   [256..320] edg  : 65-entry z_edges
#define RPW 4          // rays per wave
#define RPB 8          // rays per block (2 waves * 4)
#define RSTR 324       // per-ray LDS stride (floats); 324*4B = 1296B (16B mult)

typedef float vf4 __attribute__((ext_vector_type(4)));

__global__ __launch_bounds__(128) void hier_sampler(
    const float* __restrict__ org, const float* __restrict__ dir,
    const float* __restrict__ dens, const float* __restrict__ trand,
    const float* __restrict__ uu, float* __restrict__ out_pts,
    float* __restrict__ out_z)
{
    const int tid  = threadIdx.x;
    const int sl   = tid & 15;                 // sub-lane within ray group
    const int rloc = tid >> 4;                 // local ray id in block, 0..7
    const int ray  = blockIdx.x * RPB + rloc;

    __shared__ __align__(16) float lds[RPB * RSTR];
    float* srt  = &lds[rloc * RSTR];
    float* cdfB = srt + 192;
    float* edg  = srt + 256;

    // ---- coarse stratified sampling: 4 samples/lane, j = 4*sl+m ----
    const float step = 4.0f / 63.0f;
    const float4 t4 = ((const float4*)trand)[(size_t)ray * 16 + sl];
    const float4 d4 = ((const float4*)dens )[(size_t)ray * 16 + sl];
    const float tarr[4] = {t4.x, t4.y, t4.z, t4.w};
    const float darr[4] = {d4.x, d4.y, d4.z, d4.w};
    float zv[4];
    #pragma unroll
    for (int m = 0; m < 4; ++m) {
        int j = 4*sl + m;
        float zg = 2.0f + step * (float)j;
        float lo = (j == 0)  ? 2.0f : (zg - 0.5f*step);   // mids are zg +- step/2
        float up = (j == 63) ? 6.0f : (zg + 0.5f*step);
        zv[m] = lo + (up - lo) * tarr[m];
    }
    float znext0 = __shfl_down(zv[0], 1, 16);
    float delta[4] = { zv[1]-zv[0], zv[2]-zv[1], zv[3]-zv[2],
                       (sl == 15) ? 1e10f : (znext0 - zv[3]) };

    // ---- transmittance weights (in-lane 4 + cross-lane 16 scans) ----
    float a[4], pp[4];
    {
        float run = 1.0f;
        #pragma unroll
        for (int m = 0; m < 4; ++m) {
            a[m] = 1.0f - expf(-darr[m] * delta[m]);
            run *= (1.0f - a[m] + 1e-10f);
            pp[m] = run;                        // in-lane inclusive product
        }
    }
    float P = pp[3];
    #pragma unroll
    for (int off = 1; off < 16; off <<= 1) {
        float n = __shfl_up(P, off, 16);
        if (sl >= off) P *= n;
    }
    float E = __shfl_up(P, 1, 16);
    if (sl == 0) E = 1.0f;                      // exclusive product of lane-blocks

    float sw[4];
    {
        float acc = 0.0f;
        #pragma unroll
        for (int m = 0; m < 4; ++m) {
            float T = (m == 0) ? E : E * pp[m-1];   // exclusive cumprod at j
            acc += a[m]*T + 1e-5f;                  // w + 1e-5, in-lane cumsum
            sw[m] = acc;
        }
    }
    float S = sw[3];
    #pragma unroll
    for (int off = 1; off < 16; off <<= 1) {
        float n = __shfl_up(S, off, 16);
        if (sl >= off) S += n;
    }
    float Es = __shfl_up(S, 1, 16);
    if (sl == 0) Es = 0.0f;
    float tot  = __shfl(S, 15, 16);
    float itot = 1.0f / tot;

    *(float4*)(cdfB + 4*sl) = make_float4((Es+sw[0])*itot, (Es+sw[1])*itot,
                                          (Es+sw[2])*itot, (Es+sw[3])*itot);
    // ---- z_edges ----
    float zp3 = __shfl_up(zv[3], 1, 16);
    float ej0 = (sl == 0) ? (1.5f*zv[0] - 0.5f*zv[1]) : 0.5f*(zp3 + zv[0]);
    *(float4*)(edg + 4*sl) = make_float4(ej0, 0.5f*(zv[0]+zv[1]),
                                         0.5f*(zv[1]+zv[2]), 0.5f*(zv[2]+zv[3]));
    if (sl == 15) edg[64] = 1.5f*zv[3] - 0.5f*zv[2];
    // ---- stage coarse for sort ----
    *(float4*)(srt + 4*sl) = make_float4(zv[0], zv[1], zv[2], zv[3]);

    // ---- inverse-CDF fine sampling: 8 u's per lane ----
    // searchsorted(cdf65, u, 'right') = 1 + searchsorted_right(cdfB, u) since
    // cdf[0]=0 <= u always. lo in [0,64] after 7 steps.
    const float4 ua = ((const float4*)uu)[(size_t)ray*32 + 2*sl];
    const float4 ub = ((const float4*)uu)[(size_t)ray*32 + 2*sl + 1];
    const float uarr[8] = {ua.x,ua.y,ua.z,ua.w, ub.x,ub.y,ub.z,ub.w};
    float fz[8];
    #pragma unroll
    for (int t = 0; t < 8; ++t) {
        float u = uarr[t];
        int lo = 0, hi = 64;
        #pragma unroll
        for (int it = 0; it < 7; ++it) {
            int m = (lo + hi) >> 1;
            bool c = cdfB[m] <= u;
            lo = c ? m+1 : lo;
            hi = c ? hi  : m;
        }
        int below = lo;                          // = clip(inds-1) in [0,64]
        int above = (lo < 64) ? lo + 1 : 64;     // = clip(inds)   in [1,64]
        int bm1   = (below > 0) ? below - 1 : 0;
        float c0 = cdfB[bm1];
        if (below == 0) c0 = 0.0f;               // cdf[0] = 0
        float c1 = cdfB[above - 1];
        float e0 = edg[below], e1 = edg[above];
        float dn = c1 - c0;
        if (dn < 1e-5f) dn = 1.0f;
        float tt = (u - c0) / dn;
        fz[t] = e0 + tt * (e1 - e0);
    }
    *(float4*)(srt + 64 + 8*sl)     = make_float4(fz[0],fz[1],fz[2],fz[3]);
    *(float4*)(srt + 64 + 8*sl + 4) = make_float4(fz[4],fz[5],fz[6],fz[7]);

    // ---- load sort layout: y[h] = element 16*sl + h (pads 192..255 = 1e30) ----
    float y[16];
    if (sl < 12) {
        #pragma unroll
        for (int tq = 0; tq < 4; ++tq) {
            float4 v = *(const float4*)(srt + 16*sl + 4*tq);
            y[4*tq+0]=v.x; y[4*tq+1]=v.y; y[4*tq+2]=v.z; y[4*tq+3]=v.w;
        }
    } else {
        #pragma unroll
        for (int h = 0; h < 16; ++h) y[h] = 1.0e30f;
    }

    // ---- bitonic sort of 256, row-major 16/lane (same network as R4, V=16) ----
    // asc(e) = ((e&k)==0), tmin(e) = (((e&j)==0)==asc); e = 16*sl + h.
    #pragma unroll
    for (int k = 2; k <= 256; k <<= 1) {
        #pragma unroll
        for (int j = k >> 1; j >= 1; j >>= 1) {
            if (j >= 16) {                       // cross-lane: lm = j/16 in 1..8
                const int lm = j >> 4;
                const bool uasc = ((sl & (k >> 4)) == 0);      // k >= 32 here
                #pragma unroll
                for (int h = 0; h < 16; ++h) {
                    float p = __shfl_xor(y[h], lm);
                    const bool tmin = (((sl & lm) == 0) == uasc);
                    y[h] = tmin ? fminf(y[h], p) : fmaxf(y[h], p);
                }
            } else {                             // in-register pairs (h, h^j)
                bool dirlane = true;
                if (k == 16)      dirlane = ((sl & 1) == 0);        // e&16
                else if (k >= 32) dirlane = ((sl & (k >> 4)) == 0); // e&k
                #pragma unroll
                for (int h = 0; h < 16; ++h) {
                    if ((h & j) == 0) {
                        const int b = h ^ j;
                        const bool dr = (k <= 8) ? ((h & k) == 0) : dirlane;
                        float lo_ = fminf(y[h], y[b]);
                        float hi_ = fmaxf(y[h], y[b]);
                        y[h] = dr ? lo_ : hi_;
                        y[b] = dr ? hi_ : lo_;
                    }
                }
            }
        }
    }

    // ---- write sorted to LDS; emit sorted z straight from registers ----
    if (sl < 12) {
        size_t zb = (size_t)ray * 192 + 16*sl;
        #pragma unroll
        for (int tq = 0; tq < 4; ++tq) {
            *(float4*)(srt + 16*sl + 4*tq) =
                make_float4(y[4*tq],y[4*tq+1],y[4*tq+2],y[4*tq+3]);
            vf4 v = {y[4*tq], y[4*tq+1], y[4*tq+2], y[4*tq+3]};
            __builtin_nontemporal_store(v, (vf4*)(out_z + zb + 4*tq));
        }
    }

    // ---- emit points: per-ray group, 144 float4 chunks = 9 iterations ----
    float ox = org[(size_t)ray*3+0], oy = org[(size_t)ray*3+1], oz = org[(size_t)ray*3+2];
    float dx = dir[(size_t)ray*3+0], dy = dir[(size_t)ray*3+1], dz = dir[(size_t)ray*3+2];
    float* pbase = out_pts + (size_t)ray * 576;
    #pragma unroll
    for (int it = 0; it < 9; ++it) {
        int i  = it*16 + sl;                // chunk id 0..143, covers idx 4i..4i+3
        int q  = i / 3;
        int c0 = i - 3*q;                   // idx%3
        int k0 = i + q;                     // idx/3
        float z0 = srt[k0];
        float z1 = srt[k0+1];
        // m=0: ch=c0,z0    m=3: ch=c0,z1
        float o0  = (c0==0)?ox:((c0==1)?oy:oz);
        float dd0 = (c0==0)?dx:((c0==1)?dy:dz);
        float v0 = fmaf(dd0, z0, o0);
        float v3 = fmaf(dd0, z1, o0);
        // m=1: cm=c0+1 (wraps at 3 -> z1)
        int   c1i = (c0==2)?0:(c0+1);
        float zz1 = (c0==2)?z1:z0;
        float o1  = (c1i==0)?ox:((c1i==1)?oy:oz);
        float dd1 = (c1i==0)?dx:((c1i==1)?dy:dz);
        float v1 = fmaf(dd1, zz1, o1);
        // m=2: cm=c0+2 (wraps for c0>=1 -> z1)
        int   c2i = (c0==0)?2:(c0-1);
        float zz2 = (c0==0)?z0:z1;
        float o2  = (c2i==0)?ox:((c2i==1)?oy:oz);
        float dd2 = (c2i==0)?dx:((c2i==1)?dy:dz);
        float v2 = fmaf(dd2, zz2, o2);
        vf4 v = {v0, v1, v2, v3};
        __builtin_nontemporal_store(v, (vf4*)(pbase + 4*i));
    }
}

extern "C" void kernel_launch(void* const* d_in, const int* in_sizes, int n_in,
                              void* d_out, int out_size, void* d_ws, size_t ws_size,
                              hipStream_t stream) {
    const float* org   = (const float*)d_in[0];
    const float* dir   = (const float*)d_in[1];
    const float* dens  = (const float*)d_in[2];
    const float* trand = (const float*)d_in[3];
    const float* uv    = (const float*)d_in[4];
    int B = in_sizes[0] / 3;   // 131072

    float* out_pts = (float*)d_out;
    float* out_z   = out_pts + (size_t)B * 576;

    dim3 grid(B / RPB), block(128);
    hipLaunchKernelGGL(hier_sampler, grid, block, 0, stream,
                       org, dir, dens, trand, uv, out_pts, out_z);
}

// Round 8
// 140.089 us; speedup vs baseline: 4.1123x; 1.0319x over previous
//
#include <hip/hip_runtime.h>

// NeRF hierarchical sampler: 16 lanes per ray, 4 rays per wave64, 2 waves/block.
// All LDS traffic is wave-private (16-lane ray groups) -> no barriers needed.
// Cross-lane traffic moved to VALU via DPP where the pattern allows:
//   xor1 = quad_perm[1,0,3,2] (0xB1), xor2 = quad_perm[2,3,0,1] (0x4E),
//   xor8 = row_ror:8 (0x128), shfl_up n = row_shr:n (0x110|n),
//   shfl_down n = row_shl:n (0x100|n).  xor4 stays ds_swizzle.
// Per-ray LDS (RSTR=324 floats, 16B-aligned):
//   [0..191]   srt  : staging (coarse 64 + fine 128), later the sorted 192
//   [192..255] cdfB : cdf[1..64]  (cdf[0]=0 handled implicitly: u>=0 always)
//   [256..320] edg  : 65-entry z_edges
#define RPW 4          // rays per wave
#define RPB 8          // rays per block (2 waves * 4)
#define RSTR 324       // per-ray LDS stride (floats); 324*4B = 1296B (16B mult)

typedef float vf4 __attribute__((ext_vector_type(4)));

template<int CTRL, bool BC>
__device__ __forceinline__ float updpp(float old, float x) {
    return __int_as_float(__builtin_amdgcn_update_dpp(
        __float_as_int(old), __float_as_int(x), CTRL, 0xF, 0xF, BC));
}

__global__ __launch_bounds__(128) void hier_sampler(
    const float* __restrict__ org, const float* __restrict__ dir,
    const float* __restrict__ dens, const float* __restrict__ trand,
    const float* __restrict__ uu, float* __restrict__ out_pts,
    float* __restrict__ out_z)
{
    const int tid  = threadIdx.x;
    const int sl   = tid & 15;                 // sub-lane within ray group
    const int rloc = tid >> 4;                 // local ray id in block, 0..7
    const int ray  = blockIdx.x * RPB + rloc;

    __shared__ __align__(16) float lds[RPB * RSTR];
    float* srt  = &lds[rloc * RSTR];
    float* cdfB = srt + 192;
    float* edg  = srt + 256;

    // ---- coarse stratified sampling: 4 samples/lane, j = 4*sl+m ----
    const float step = 4.0f / 63.0f;
    const float4 t4 = ((const float4*)trand)[(size_t)ray * 16 + sl];
    const float4 d4 = ((const float4*)dens )[(size_t)ray * 16 + sl];
    const float tarr[4] = {t4.x, t4.y, t4.z, t4.w};
    const float darr[4] = {d4.x, d4.y, d4.z, d4.w};
    float zv[4];
    #pragma unroll
    for (int m = 0; m < 4; ++m) {
        int j = 4*sl + m;
        float zg = 2.0f + step * (float)j;
        float lo = (j == 0)  ? 2.0f : (zg - 0.5f*step);   // mids are zg +- step/2
        float up = (j == 63) ? 6.0f : (zg + 0.5f*step);
        zv[m] = lo + (up - lo) * tarr[m];
    }
    float znext0 = updpp<0x101,true>(0.0f, zv[0]);        // shfl_down 1 (sl15 masked)
    float delta[4] = { zv[1]-zv[0], zv[2]-zv[1], zv[3]-zv[2],
                       (sl == 15) ? 1e10f : (znext0 - zv[3]) };

    // ---- transmittance weights (in-lane 4 + cross-lane 16 scans) ----
    float a[4], pp[4];
    {
        float run = 1.0f;
        #pragma unroll
        for (int m = 0; m < 4; ++m) {
            a[m] = 1.0f - __expf(-darr[m] * delta[m]);
            run *= (1.0f - a[m] + 1e-10f);
            pp[m] = run;                        // in-lane inclusive product
        }
    }
    // Hillis-Steele inclusive product scan over 16 lanes, identity=1.0
    float P = pp[3];
    P *= updpp<0x111,false>(1.0f, P);
    P *= updpp<0x112,false>(1.0f, P);
    P *= updpp<0x114,false>(1.0f, P);
    P *= updpp<0x118,false>(1.0f, P);
    float E = updpp<0x111,false>(1.0f, P);      // exclusive; sl==0 -> 1.0

    float sw[4];
    {
        float acc = 0.0f;
        #pragma unroll
        for (int m = 0; m < 4; ++m) {
            float T = (m == 0) ? E : E * pp[m-1];   // exclusive cumprod at j
            acc += a[m]*T + 1e-5f;                  // w + 1e-5, in-lane cumsum
            sw[m] = acc;
        }
    }
    // inclusive sum scan over 16 lanes, identity=0.0
    float S = sw[3];
    S += updpp<0x111,false>(0.0f, S);
    S += updpp<0x112,false>(0.0f, S);
    S += updpp<0x114,false>(0.0f, S);
    S += updpp<0x118,false>(0.0f, S);
    float Es  = updpp<0x111,false>(0.0f, S);    // exclusive; sl==0 -> 0
    float tot = __shfl(S, 15, 16);
    float itot = 1.0f / tot;

    *(float4*)(cdfB + 4*sl) = make_float4((Es+sw[0])*itot, (Es+sw[1])*itot,
                                          (Es+sw[2])*itot, (Es+sw[3])*itot);
    // ---- z_edges ----
    float zp3 = updpp<0x111,true>(0.0f, zv[3]); // shfl_up 1 (sl0 masked)
    float ej0 = (sl == 0) ? (1.5f*zv[0] - 0.5f*zv[1]) : 0.5f*(zp3 + zv[0]);
    *(float4*)(edg + 4*sl) = make_float4(ej0, 0.5f*(zv[0]+zv[1]),
                                         0.5f*(zv[1]+zv[2]), 0.5f*(zv[2]+zv[3]));
    if (sl == 15) edg[64] = 1.5f*zv[3] - 0.5f*zv[2];
    // ---- stage coarse for sort ----
    *(float4*)(srt + 4*sl) = make_float4(zv[0], zv[1], zv[2], zv[3]);

    // ---- inverse-CDF fine sampling: 8 u's per lane ----
    // searchsorted(cdf65, u, 'right') = 1 + searchsorted_right(cdfB, u) since
    // cdf[0]=0 <= u always. lo in [0,64] after 7 steps.
    const float4 ua = ((const float4*)uu)[(size_t)ray*32 + 2*sl];
    const float4 ub = ((const float4*)uu)[(size_t)ray*32 + 2*sl + 1];
    const float uarr[8] = {ua.x,ua.y,ua.z,ua.w, ub.x,ub.y,ub.z,ub.w};
    float fz[8];
    #pragma unroll
    for (int t = 0; t < 8; ++t) {
        float u = uarr[t];
        int lo = 0, hi = 64;
        #pragma unroll
        for (int it = 0; it < 7; ++it) {
            int m = (lo + hi) >> 1;
            bool c = cdfB[m] <= u;
            lo = c ? m+1 : lo;
            hi = c ? hi  : m;
        }
        int below = lo;                          // = clip(inds-1) in [0,64]
        int above = (lo < 64) ? lo + 1 : 64;     // = clip(inds)   in [1,64]
        int bm1   = (below > 0) ? below - 1 : 0;
        float c0 = cdfB[bm1];
        if (below == 0) c0 = 0.0f;               // cdf[0] = 0
        float c1 = cdfB[above - 1];
        float e0 = edg[below], e1 = edg[above];
        float dn = c1 - c0;
        if (dn < 1e-5f) dn = 1.0f;
        float tt = (u - c0) / dn;
        fz[t] = e0 + tt * (e1 - e0);
    }
    *(float4*)(srt + 64 + 8*sl)     = make_float4(fz[0],fz[1],fz[2],fz[3]);
    *(float4*)(srt + 64 + 8*sl + 4) = make_float4(fz[4],fz[5],fz[6],fz[7]);

    // ---- load sort layout: y[h] = element 16*sl + h (pads 192..255 = 1e30) ----
    float y[16];
    if (sl < 12) {
        #pragma unroll
        for (int tq = 0; tq < 4; ++tq) {
            float4 v = *(const float4*)(srt + 16*sl + 4*tq);
            y[4*tq+0]=v.x; y[4*tq+1]=v.y; y[4*tq+2]=v.z; y[4*tq+3]=v.w;
        }
    } else {
        #pragma unroll
        for (int h = 0; h < 16; ++h) y[h] = 1.0e30f;
    }

    // ---- bitonic sort of 256, row-major 16/lane (same network as R6) ----
    // asc(e) = ((e&k)==0), tmin(e) = (((e&j)==0)==asc); e = 16*sl + h.
    #pragma unroll
    for (int k = 2; k <= 256; k <<= 1) {
        #pragma unroll
        for (int j = k >> 1; j >= 1; j >>= 1) {
            if (j >= 16) {                       // cross-lane: lm = j/16 in 1..8
                const int lm = j >> 4;
                const bool uasc = ((sl & (k >> 4)) == 0);      // k >= 32 here
                #pragma unroll
                for (int h = 0; h < 16; ++h) {
                    float p;
                    if      (lm == 1) p = updpp<0xB1, true>(0.0f, y[h]); // xor1
                    else if (lm == 2) p = updpp<0x4E, true>(0.0f, y[h]); // xor2
                    else if (lm == 8) p = updpp<0x128,true>(0.0f, y[h]); // xor8
                    else              p = __shfl_xor(y[h], 4);           // xor4
                    const bool tmin = (((sl & lm) == 0) == uasc);
                    y[h] = tmin ? fminf(y[h], p) : fmaxf(y[h], p);
                }
            } else {                             // in-register pairs (h, h^j)
                bool dirlane = true;
                if (k == 16)      dirlane = ((sl & 1) == 0);        // e&16
                else if (k >= 32) dirlane = ((sl & (k >> 4)) == 0); // e&k
                #pragma unroll
                for (int h = 0; h < 16; ++h) {
                    if ((h & j) == 0) {
                        const int b = h ^ j;
                        const bool dr = (k <= 8) ? ((h & k) == 0) : dirlane;
                        float lo_ = fminf(y[h], y[b]);
                        float hi_ = fmaxf(y[h], y[b]);
                        y[h] = dr ? lo_ : hi_;
                        y[b] = dr ? hi_ : lo_;
                    }
                }
            }
        }
    }

    // ---- write sorted to LDS; emit sorted z straight from registers ----
    if (sl < 12) {
        size_t zb = (size_t)ray * 192 + 16*sl;
        #pragma unroll
        for (int tq = 0; tq < 4; ++tq) {
            *(float4*)(srt + 16*sl + 4*tq) =
                make_float4(y[4*tq],y[4*tq+1],y[4*tq+2],y[4*tq+3]);
            vf4 v = {y[4*tq], y[4*tq+1], y[4*tq+2], y[4*tq+3]};
            __builtin_nontemporal_store(v, (vf4*)(out_z + zb + 4*tq));
        }
    }

    // ---- emit points: per-ray group, 144 float4 chunks = 9 iterations ----
    float ox = org[(size_t)ray*3+0], oy = org[(size_t)ray*3+1], oz = org[(size_t)ray*3+2];
    float dx = dir[(size_t)ray*3+0], dy = dir[(size_t)ray*3+1], dz = dir[(size_t)ray*3+2];
    float* pbase = out_pts + (size_t)ray * 576;
    #pragma unroll
    for (int it = 0; it < 9; ++it) {
        int i  = it*16 + sl;                // chunk id 0..143, covers idx 4i..4i+3
        int q  = i / 3;
        int c0 = i - 3*q;                   // idx%3
        int k0 = i + q;                     // idx/3
        float z0 = srt[k0];
        float z1 = srt[k0+1];
        // m=0: ch=c0,z0    m=3: ch=c0,z1
        float o0  = (c0==0)?ox:((c0==1)?oy:oz);
        float dd0 = (c0==0)?dx:((c0==1)?dy:dz);
        float v0 = fmaf(dd0, z0, o0);
        float v3 = fmaf(dd0, z1, o0);
        // m=1: cm=c0+1 (wraps at 3 -> z1)
        int   c1i = (c0==2)?0:(c0+1);
        float zz1 = (c0==2)?z1:z0;
        float o1  = (c1i==0)?ox:((c1i==1)?oy:oz);
        float dd1 = (c1i==0)?dx:((c1i==1)?dy:dz);
        float v1 = fmaf(dd1, zz1, o1);
        // m=2: cm=c0+2 (wraps for c0>=1 -> z1)
        int   c2i = (c0==0)?2:(c0-1);
        float zz2 = (c0==0)?z0:z1;
        float o2  = (c2i==0)?ox:((c2i==1)?oy:oz);
        float dd2 = (c2i==0)?dx:((c2i==1)?dy:dz);
        float v2 = fmaf(dd2, zz2, o2);
        vf4 v = {v0, v1, v2, v3};
        __builtin_nontemporal_store(v, (vf4*)(pbase + 4*i));
    }
}

extern "C" void kernel_launch(void* const* d_in, const int* in_sizes, int n_in,
                              void* d_out, int out_size, void* d_ws, size_t ws_size,
                              hipStream_t stream) {
    const float* org   = (const float*)d_in[0];
    const float* dir   = (const float*)d_in[1];
    const float* dens  = (const float*)d_in[2];
    const float* trand = (const float*)d_in[3];
    const float* uv    = (const float*)d_in[4];
    int B = in_sizes[0] / 3;   // 131072

    float* out_pts = (float*)d_out;
    float* out_z   = out_pts + (size_t)B * 576;

    dim3 grid(B / RPB), block(128);
    hipLaunchKernelGGL(hier_sampler, grid, block, 0, stream,
                       org, dir, dens, trand, uv, out_pts, out_z);
}